// Round 1
// baseline (2429.069 us; speedup 1.0000x reference)
//
#include <hip/hip_runtime.h>
#include <stdint.h>

// Match XLA: no FMA contraction anywhere numerics feed comparisons.
#pragma clang fp contract(off)

#define B_IMG 32
#define R_N   6000
#define G_N   100
#define NS    128
#define PMAX  32
#define NBUCK 1024

// JAX >= 0.4.36 defaults jax_threefry_partitionable=True. Flip to 0 if the
// harness's JAX uses the original (non-partitionable) threefry path.
#ifndef JAX_PARTITIONABLE
#define JAX_PARTITIONABLE 1
#endif

__device__ __forceinline__ uint32_t rotl32(uint32_t v, int d) {
  return (v << d) | (v >> (32 - d));
}

// Threefry-2x32, 20 rounds, exactly as jax/_src/prng.py
__device__ __forceinline__ void tf2x32(uint32_t k0, uint32_t k1,
                                       uint32_t x0, uint32_t x1,
                                       uint32_t& o0, uint32_t& o1) {
  const uint32_t k2 = k0 ^ k1 ^ 0x1BD11BDAu;
  x0 += k0; x1 += k1;
#define TF_R(r) { x0 += x1; x1 = rotl32(x1, r); x1 ^= x0; }
  TF_R(13) TF_R(15) TF_R(26) TF_R(6)
  x0 += k1; x1 += k2 + 1u;
  TF_R(17) TF_R(29) TF_R(16) TF_R(24)
  x0 += k2; x1 += k0 + 2u;
  TF_R(13) TF_R(15) TF_R(26) TF_R(6)
  x0 += k0; x1 += k1 + 3u;
  TF_R(17) TF_R(29) TF_R(16) TF_R(24)
  x0 += k1; x1 += k2 + 4u;
  TF_R(13) TF_R(15) TF_R(26) TF_R(6)
  x0 += k2; x1 += k0 + 5u;
#undef TF_R
  o0 = x0; o1 = x1;
}

// jax.random.uniform transform for float32, minval=1e-6, maxval=1.0
__device__ __forceinline__ float tf_uniform(uint32_t bits) {
#pragma clang fp contract(off)
  float f = __uint_as_float((bits >> 9) | 0x3f800000u) - 1.0f;
  float r = f * (1.0f - 1e-6f) + 1e-6f;   // mul then add, NOT fma
  return fmaxf(1e-6f, r);
}

// Kernel 1: per-roi r (threefry), IOU max + argmax vs 100 GTs.
__global__ __launch_bounds__(256) void prep_kernel(
    const float* __restrict__ roi, const float* __restrict__ gt,
    float* __restrict__ wr, float* __restrict__ wmiou, int* __restrict__ wgta) {
#pragma clang fp contract(off)
  const int b = blockIdx.y;
  const int i = blockIdx.x * 256 + threadIdx.x;

  __shared__ float sg[G_N * 4];
  __shared__ float sga[G_N];
  for (int t = threadIdx.x; t < G_N * 4; t += 256) sg[t] = gt[b * G_N * 4 + t];
  __syncthreads();
  if (threadIdx.x < G_N) {
    int g = threadIdx.x;
    sga[g] = (sg[g * 4 + 2] - sg[g * 4 + 0]) * (sg[g * 4 + 3] - sg[g * 4 + 1]);
  }
  __syncthreads();
  if (i >= R_N) return;

  const float* rp = roi + ((size_t)b * R_N + i) * 4;
  float x1 = rp[0], y1 = rp[1], x2 = rp[2], y2 = rp[3];
  float ar = (x2 - x1) * (y2 - y1);

  float best = -1.0f; int bi = 0;
  for (int g = 0; g < G_N; ++g) {
    float gx1 = sg[g * 4 + 0], gy1 = sg[g * 4 + 1];
    float gx2 = sg[g * 4 + 2], gy2 = sg[g * 4 + 3];
    float ix1 = fmaxf(x1, gx1), iy1 = fmaxf(y1, gy1);
    float ix2 = fminf(x2, gx2), iy2 = fminf(y2, gy2);
    float iw = fmaxf(ix2 - ix1, 0.0f);
    float ih = fmaxf(iy2 - iy1, 0.0f);
    float inter = iw * ih;
    float denom = (ar + sga[g]) - inter;
    float iou = inter / denom;
    if (iou > best) { best = iou; bi = g; }  // first-max like jnp.argmax
  }

  uint32_t bits;
#if JAX_PARTITIONABLE
  uint32_t kb0, kb1;
  tf2x32(0u, 42u, 0u, (uint32_t)b, kb0, kb1);        // foldlike split: key_b
  uint32_t t0, t1;
  tf2x32(kb0, kb1, 0u, (uint32_t)i, t0, t1);
  bits = t0 ^ t1;                                    // 32-bit partitionable bits
#else
  uint32_t kb0, kb1, d0, d1;
  if (b < 16) {
    tf2x32(0u, 42u, (uint32_t)(2 * b),     (uint32_t)(2 * b + 32), kb0, d0);
    tf2x32(0u, 42u, (uint32_t)(2 * b + 1), (uint32_t)(2 * b + 33), kb1, d1);
  } else {
    int c = b - 16;
    tf2x32(0u, 42u, (uint32_t)(2 * c),     (uint32_t)(2 * c + 32), d0, kb0);
    tf2x32(0u, 42u, (uint32_t)(2 * c + 1), (uint32_t)(2 * c + 33), d1, kb1);
  }
  uint32_t t0, t1;
  if (i < R_N / 2) { tf2x32(kb0, kb1, (uint32_t)i, (uint32_t)(i + R_N / 2), t0, t1); bits = t0; }
  else             { tf2x32(kb0, kb1, (uint32_t)(i - R_N / 2), (uint32_t)i, t0, t1); bits = t1; }
#endif

  size_t o = (size_t)b * R_N + i;
  wr[o] = tf_uniform(bits);
  wmiou[o] = best;
  wgta[o] = bi;
}

// Kernel 2: per-image selection, ordering, and output write. 1 block / image.
__global__ __launch_bounds__(256) void select_kernel(
    const float* __restrict__ roi, const float* __restrict__ gt,
    const int* __restrict__ labels,
    const float* __restrict__ wr, const float* __restrict__ wmiou,
    const int* __restrict__ wgta, float* __restrict__ out) {
#pragma clang fp contract(off)
  const int b = blockIdx.x;
  const int tid = threadIdx.x;

  __shared__ float sr[R_N];
  __shared__ unsigned char scls[R_N];  // 1 = positive (max_iou >= 0.5)
  __shared__ unsigned char ssel[R_N];
  __shared__ int hist[NBUCK];
  __shared__ int sh_cntpos;
  __shared__ int sh_B, sh_A;
  __shared__ int posList[PMAX];
  __shared__ int negList[NS];
  __shared__ int listCnt[2];   // [0]=neg, [1]=pos
  __shared__ int outIdx[NS];

  if (tid == 0) sh_cntpos = 0;
  if (tid < 2) listCnt[tid] = 0;
  __syncthreads();

  int mycnt = 0;
  for (int i = tid; i < R_N; i += 256) {
    sr[i] = wr[(size_t)b * R_N + i];
    unsigned char p = (wmiou[(size_t)b * R_N + i] >= 0.5f) ? 1 : 0;
    scls[i] = p;
    ssel[i] = 0;
    mycnt += p;
  }
  atomicAdd(&sh_cntpos, mycnt);
  __syncthreads();

  const int cntPos = sh_cntpos;
  const int cntNeg = R_N - cntPos;
  const int nPosSel = min(cntPos, PMAX);
  const int Kneg = NS - nPosSel;

  // Select top-quota by (r desc, idx asc) within each class.
  for (int c = 1; c >= 0; --c) {
    const int quota = (c == 1) ? PMAX : Kneg;
    const int cnt   = (c == 1) ? cntPos : cntNeg;
    if (cnt <= quota) {
      for (int i = tid; i < R_N; i += 256)
        if (scls[i] == (unsigned char)c) ssel[i] = 1;
      __syncthreads();
      continue;
    }
    for (int h = tid; h < NBUCK; h += 256) hist[h] = 0;
    __syncthreads();
    for (int i = tid; i < R_N; i += 256)
      if (scls[i] == (unsigned char)c) {
        int bk = min((int)(sr[i] * (float)NBUCK), NBUCK - 1);
        atomicAdd(&hist[bk], 1);
      }
    __syncthreads();
    if (tid == 0) {
      int acc = 0, Bb = 0, A = 0;
      for (int h = NBUCK - 1; h >= 0; --h) {
        if (acc + hist[h] >= quota) { Bb = h; A = acc; break; }
        acc += hist[h];
      }
      sh_B = Bb; sh_A = A;
    }
    __syncthreads();
    const int Bb = sh_B, A = sh_A;
    for (int i = tid; i < R_N; i += 256)
      if (scls[i] == (unsigned char)c) {
        int bk = min((int)(sr[i] * (float)NBUCK), NBUCK - 1);
        if (bk > Bb) ssel[i] = 1;
        else if (bk == Bb) {
          float ri = sr[i];
          int beats = 0;
          for (int j = 0; j < R_N; ++j) {
            if (scls[j] == (unsigned char)c) {
              float rj = sr[j];
              int bj = min((int)(rj * (float)NBUCK), NBUCK - 1);
              if (bj == Bb && (rj > ri || (rj == ri && j < i))) beats++;
            }
          }
          if (A + beats < quota) ssel[i] = 1;
        }
      }
    __syncthreads();
  }

  // Compact selected indices per class.
  for (int i = tid; i < R_N; i += 256)
    if (ssel[i]) {
      if (scls[i]) { int p = atomicAdd(&listCnt[1], 1); if (p < PMAX) posList[p] = i; }
      else         { int p = atomicAdd(&listCnt[0], 1); if (p < NS)   negList[p] = i; }
    }
  __syncthreads();
  const int nP = min(listCnt[1], PMAX);
  const int nN = min(listCnt[0], NS);

  if (tid < NS) outIdx[tid] = -1;
  __syncthreads();

  // Output slots: top_k on prio (2+r pos, 1+r neg), ties -> lower index first.
  // Note: prio is the float32-rounded sum; distinct r can tie here.
  if (tid < nP) {
    int i = posList[tid];
    float pr = 2.0f + sr[i];
    int slot = 0;
    for (int u = 0; u < nP; ++u) {
      int j = posList[u];
      float pj = 2.0f + sr[j];
      if (pj > pr || (pj == pr && j < i)) slot++;
    }
    outIdx[slot] = i;
  }
  if (tid < nN) {
    int i = negList[tid];
    float pr = 1.0f + sr[i];
    int slot = 0;
    for (int u = 0; u < nN; ++u) {
      int j = negList[u];
      float pj = 1.0f + sr[j];
      if (pj > pr || (pj == pr && j < i)) slot++;
    }
    outIdx[nP + slot] = i;
  }
  __syncthreads();

  // Epilogue: write all three outputs (zeros for invalid filler slots).
  if (tid < NS) {
    const int p = tid;
    const int i = outIdx[p];
    float o_roi[4] = {0.f, 0.f, 0.f, 0.f};
    float o_lab = 0.f;
    float o_d[4] = {0.f, 0.f, 0.f, 0.f};
    if (i >= 0) {
      const float* rp = roi + ((size_t)b * R_N + i) * 4;
      float x1 = rp[0], y1 = rp[1], x2 = rp[2], y2 = rp[3];
      o_roi[0] = x1; o_roi[1] = y1; o_roi[2] = x2; o_roi[3] = y2;
      int g = wgta[(size_t)b * R_N + i];
      const float* gp = gt + ((size_t)b * G_N + g) * 4;
      float gx1 = gp[0], gy1 = gp[1], gx2 = gp[2], gy2 = gp[3];
      if (scls[i]) o_lab = (float)labels[b * G_N + g];
      const float EPSF = 1.1920928955078125e-7f;  // np.finfo(f32).eps
      float w = fmaxf(x2 - x1, EPSF);
      float h = fmaxf(y2 - y1, EPSF);
      float cx = x1 + 0.5f * (x2 - x1);
      float cy = y1 + 0.5f * (y2 - y1);
      float bw = gx2 - gx1, bh = gy2 - gy1;
      float bcx = gx1 + 0.5f * bw, bcy = gy1 + 0.5f * bh;
      o_d[0] = (bcx - cx) / w;
      o_d[1] = (bcy - cy) / h;
      o_d[2] = logf(bw / w);
      o_d[3] = logf(bh / h);
    }
    float* out0 = out;                         // [32,128,4]
    float* out1 = out + (size_t)B_IMG * NS * 4;        // [32,128]
    float* out2 = out1 + (size_t)B_IMG * NS;           // [32,128,4]
    const int base = b * NS + p;
    out0[base * 4 + 0] = o_roi[0];
    out0[base * 4 + 1] = o_roi[1];
    out0[base * 4 + 2] = o_roi[2];
    out0[base * 4 + 3] = o_roi[3];
    out1[base] = o_lab;
    out2[base * 4 + 0] = o_d[0];
    out2[base * 4 + 1] = o_d[1];
    out2[base * 4 + 2] = o_d[2];
    out2[base * 4 + 3] = o_d[3];
  }
}

extern "C" void kernel_launch(void* const* d_in, const int* in_sizes, int n_in,
                              void* d_out, int out_size, void* d_ws, size_t ws_size,
                              hipStream_t stream) {
  const float* roi    = (const float*)d_in[0];
  const float* gt     = (const float*)d_in[1];
  const int*   labels = (const int*)d_in[2];
  // d_in[3] (image) is unused by the math.

  float* wr    = (float*)d_ws;                  // [32*6000] r values
  float* wmiou = wr + (size_t)B_IMG * R_N;      // [32*6000] max IOU
  int*   wgta  = (int*)(wmiou + (size_t)B_IMG * R_N);  // [32*6000] argmax gt

  dim3 g1((R_N + 255) / 256, B_IMG);
  prep_kernel<<<g1, 256, 0, stream>>>(roi, gt, wr, wmiou, wgta);
  select_kernel<<<B_IMG, 256, 0, stream>>>(roi, gt, labels, wr, wmiou, wgta,
                                           (float*)d_out);
}

// Round 2
// 107.401 us; speedup vs baseline: 22.6169x; 22.6169x over previous
//
#include <hip/hip_runtime.h>
#include <stdint.h>

// Match XLA: no FMA contraction anywhere numerics feed comparisons.
#pragma clang fp contract(off)

#define B_IMG 32
#define R_N   6000
#define G_N   100
#define NS    128
#define PMAX  32
#define NBUCK 1024
#define BCAP  512
#define SEL_T 1024   // select_kernel block size

#ifndef JAX_PARTITIONABLE
#define JAX_PARTITIONABLE 1
#endif

__device__ __forceinline__ uint32_t rotl32(uint32_t v, int d) {
  return (v << d) | (v >> (32 - d));
}

// Threefry-2x32, 20 rounds, exactly as jax/_src/prng.py
__device__ __forceinline__ void tf2x32(uint32_t k0, uint32_t k1,
                                       uint32_t x0, uint32_t x1,
                                       uint32_t& o0, uint32_t& o1) {
  const uint32_t k2 = k0 ^ k1 ^ 0x1BD11BDAu;
  x0 += k0; x1 += k1;
#define TF_R(r) { x0 += x1; x1 = rotl32(x1, r); x1 ^= x0; }
  TF_R(13) TF_R(15) TF_R(26) TF_R(6)
  x0 += k1; x1 += k2 + 1u;
  TF_R(17) TF_R(29) TF_R(16) TF_R(24)
  x0 += k2; x1 += k0 + 2u;
  TF_R(13) TF_R(15) TF_R(26) TF_R(6)
  x0 += k0; x1 += k1 + 3u;
  TF_R(17) TF_R(29) TF_R(16) TF_R(24)
  x0 += k1; x1 += k2 + 4u;
  TF_R(13) TF_R(15) TF_R(26) TF_R(6)
  x0 += k2; x1 += k0 + 5u;
#undef TF_R
  o0 = x0; o1 = x1;
}

// jax.random.uniform transform for float32, minval=1e-6, maxval=1.0
__device__ __forceinline__ float tf_uniform(uint32_t bits) {
#pragma clang fp contract(off)
  float f = __uint_as_float((bits >> 9) | 0x3f800000u) - 1.0f;
  float r = f * (1.0f - 1e-6f) + 1e-6f;   // mul then add, NOT fma
  return fmaxf(1e-6f, r);
}

// Kernel 1: per-roi r (threefry), IOU max + argmax vs 100 GTs.
__global__ __launch_bounds__(256) void prep_kernel(
    const float* __restrict__ roi, const float* __restrict__ gt,
    float* __restrict__ wr, float* __restrict__ wmiou, int* __restrict__ wgta) {
#pragma clang fp contract(off)
  const int b = blockIdx.y;
  const int i = blockIdx.x * 256 + threadIdx.x;

  __shared__ float sg[G_N * 4];
  __shared__ float sga[G_N];
  for (int t = threadIdx.x; t < G_N * 4; t += 256) sg[t] = gt[b * G_N * 4 + t];
  __syncthreads();
  if (threadIdx.x < G_N) {
    int g = threadIdx.x;
    sga[g] = (sg[g * 4 + 2] - sg[g * 4 + 0]) * (sg[g * 4 + 3] - sg[g * 4 + 1]);
  }
  __syncthreads();
  if (i >= R_N) return;

  const float* rp = roi + ((size_t)b * R_N + i) * 4;
  float x1 = rp[0], y1 = rp[1], x2 = rp[2], y2 = rp[3];
  float ar = (x2 - x1) * (y2 - y1);

  float best = -1.0f; int bi = 0;
  for (int g = 0; g < G_N; ++g) {
    float gx1 = sg[g * 4 + 0], gy1 = sg[g * 4 + 1];
    float gx2 = sg[g * 4 + 2], gy2 = sg[g * 4 + 3];
    float ix1 = fmaxf(x1, gx1), iy1 = fmaxf(y1, gy1);
    float ix2 = fminf(x2, gx2), iy2 = fminf(y2, gy2);
    float iw = fmaxf(ix2 - ix1, 0.0f);
    float ih = fmaxf(iy2 - iy1, 0.0f);
    float inter = iw * ih;
    float denom = (ar + sga[g]) - inter;
    float iou = inter / denom;
    if (iou > best) { best = iou; bi = g; }  // first-max like jnp.argmax
  }

  uint32_t bits;
#if JAX_PARTITIONABLE
  uint32_t kb0, kb1;
  tf2x32(0u, 42u, 0u, (uint32_t)b, kb0, kb1);        // foldlike split: key_b
  uint32_t t0, t1;
  tf2x32(kb0, kb1, 0u, (uint32_t)i, t0, t1);
  bits = t0 ^ t1;                                    // 32-bit partitionable bits
#else
  uint32_t kb0, kb1, d0, d1;
  if (b < 16) {
    tf2x32(0u, 42u, (uint32_t)(2 * b),     (uint32_t)(2 * b + 32), kb0, d0);
    tf2x32(0u, 42u, (uint32_t)(2 * b + 1), (uint32_t)(2 * b + 33), kb1, d1);
  } else {
    int c = b - 16;
    tf2x32(0u, 42u, (uint32_t)(2 * c),     (uint32_t)(2 * c + 32), d0, kb0);
    tf2x32(0u, 42u, (uint32_t)(2 * c + 1), (uint32_t)(2 * c + 33), d1, kb1);
  }
  uint32_t t0, t1;
  if (i < R_N / 2) { tf2x32(kb0, kb1, (uint32_t)i, (uint32_t)(i + R_N / 2), t0, t1); bits = t0; }
  else             { tf2x32(kb0, kb1, (uint32_t)(i - R_N / 2), (uint32_t)i, t0, t1); bits = t1; }
#endif

  size_t o = (size_t)b * R_N + i;
  wr[o] = tf_uniform(bits);
  wmiou[o] = best;
  wgta[o] = bi;
}

// Kernel 2: per-image selection, ordering, and output write. 1 block / image.
__global__ __launch_bounds__(SEL_T) void select_kernel(
    const float* __restrict__ roi, const float* __restrict__ gt,
    const int* __restrict__ labels,
    const float* __restrict__ wr, const float* __restrict__ wmiou,
    const int* __restrict__ wgta, float* __restrict__ out) {
#pragma clang fp contract(off)
  const int b = blockIdx.x;
  const int tid = threadIdx.x;

  __shared__ float sr[R_N];
  __shared__ unsigned char scls[R_N];  // 1 = positive (max_iou >= 0.5)
  __shared__ unsigned char ssel[R_N];
  __shared__ int S[NBUCK];             // histogram, then suffix sums
  __shared__ int sh_cntpos;
  __shared__ int sh_B, sh_A;
  __shared__ int candIdx[BCAP];
  __shared__ int candCnt;
  __shared__ int posList[PMAX];
  __shared__ int negList[NS];
  __shared__ int listCnt[2];   // [0]=neg, [1]=pos
  __shared__ int outIdx[NS];

  if (tid == 0) sh_cntpos = 0;
  if (tid < 2) listCnt[tid] = 0;
  __syncthreads();

  int mycnt = 0;
  for (int i = tid; i < R_N; i += SEL_T) {
    sr[i] = wr[(size_t)b * R_N + i];
    unsigned char p = (wmiou[(size_t)b * R_N + i] >= 0.5f) ? 1 : 0;
    scls[i] = p;
    ssel[i] = 0;
    mycnt += p;
  }
  if (mycnt) atomicAdd(&sh_cntpos, mycnt);
  __syncthreads();

  const int cntPos = sh_cntpos;
  const int cntNeg = R_N - cntPos;
  const int nPosSel = min(cntPos, PMAX);
  const int Kneg = NS - nPosSel;

  // Select top-quota by (r desc, idx asc) within each class.
  for (int c = 1; c >= 0; --c) {
    const int quota = (c == 1) ? PMAX : Kneg;
    const int cnt   = (c == 1) ? cntPos : cntNeg;
    if (cnt <= quota) {
      for (int i = tid; i < R_N; i += SEL_T)
        if (scls[i] == (unsigned char)c) ssel[i] = 1;
      __syncthreads();
      continue;
    }
    // --- histogram ---
    if (tid < NBUCK) S[tid] = 0;
    if (tid == 0) candCnt = 0;
    __syncthreads();
    for (int i = tid; i < R_N; i += SEL_T)
      if (scls[i] == (unsigned char)c) {
        int bk = min((int)(sr[i] * (float)NBUCK), NBUCK - 1);
        atomicAdd(&S[bk], 1);
      }
    __syncthreads();
    // --- parallel suffix sum over buckets (Hillis-Steele) ---
    for (int off = 1; off < NBUCK; off <<= 1) {
      int v = 0;
      if (tid < NBUCK && tid + off < NBUCK) v = S[tid + off];
      __syncthreads();
      if (tid < NBUCK) S[tid] += v;
      __syncthreads();
    }
    // unique boundary bucket: S[h] >= quota, S[h+1] < quota
    if (tid < NBUCK) {
      int Sh = S[tid];
      int Sn = (tid + 1 < NBUCK) ? S[tid + 1] : 0;
      if (Sh >= quota && Sn < quota) { sh_B = tid; sh_A = Sn; }
    }
    __syncthreads();
    const int Bb = sh_B, A = sh_A;
    // --- mark definite winners; compact boundary bucket ---
    for (int i = tid; i < R_N; i += SEL_T)
      if (scls[i] == (unsigned char)c) {
        int bk = min((int)(sr[i] * (float)NBUCK), NBUCK - 1);
        if (bk > Bb) ssel[i] = 1;
        else if (bk == Bb) {
          int p = atomicAdd(&candCnt, 1);
          if (p < BCAP) candIdx[p] = i;
        }
      }
    __syncthreads();
    const int M = candCnt;
    if (M <= BCAP) {
      // exact rank among the small boundary list: O(M^2), M ~ 6
      if (tid < M) {
        int i = candIdx[tid];
        float ri = sr[i];
        int beats = 0;
        for (int u = 0; u < M; ++u) {
          int j = candIdx[u];
          float rj = sr[j];
          if (rj > ri || (rj == ri && j < i)) beats++;
        }
        if (A + beats < quota) ssel[i] = 1;
      }
    } else {
      // fallback (statistically never): full scan per boundary candidate
      for (int i = tid; i < R_N; i += SEL_T)
        if (scls[i] == (unsigned char)c) {
          int bk = min((int)(sr[i] * (float)NBUCK), NBUCK - 1);
          if (bk == Bb) {
            float ri = sr[i];
            int beats = 0;
            for (int j = 0; j < R_N; ++j)
              if (scls[j] == (unsigned char)c) {
                float rj = sr[j];
                int bj = min((int)(rj * (float)NBUCK), NBUCK - 1);
                if (bj == Bb && (rj > ri || (rj == ri && j < i))) beats++;
              }
            if (A + beats < quota) ssel[i] = 1;
          }
        }
    }
    __syncthreads();
  }

  // Compact selected indices per class.
  for (int i = tid; i < R_N; i += SEL_T)
    if (ssel[i]) {
      if (scls[i]) { int p = atomicAdd(&listCnt[1], 1); if (p < PMAX) posList[p] = i; }
      else         { int p = atomicAdd(&listCnt[0], 1); if (p < NS)   negList[p] = i; }
    }
  __syncthreads();
  const int nP = min(listCnt[1], PMAX);
  const int nN = min(listCnt[0], NS);

  if (tid < NS) outIdx[tid] = -1;
  __syncthreads();

  // Output slots: top_k on prio (2+r pos, 1+r neg), ties -> lower index first.
  // Note: prio is the float32-rounded sum; distinct r can tie here.
  if (tid < nP) {
    int i = posList[tid];
    float pr = 2.0f + sr[i];
    int slot = 0;
    for (int u = 0; u < nP; ++u) {
      int j = posList[u];
      float pj = 2.0f + sr[j];
      if (pj > pr || (pj == pr && j < i)) slot++;
    }
    outIdx[slot] = i;
  }
  if (tid < nN) {
    int i = negList[tid];
    float pr = 1.0f + sr[i];
    int slot = 0;
    for (int u = 0; u < nN; ++u) {
      int j = negList[u];
      float pj = 1.0f + sr[j];
      if (pj > pr || (pj == pr && j < i)) slot++;
    }
    outIdx[nP + slot] = i;
  }
  __syncthreads();

  // Epilogue: write all three outputs (zeros for invalid filler slots).
  if (tid < NS) {
    const int p = tid;
    const int i = outIdx[p];
    float o_roi[4] = {0.f, 0.f, 0.f, 0.f};
    float o_lab = 0.f;
    float o_d[4] = {0.f, 0.f, 0.f, 0.f};
    if (i >= 0) {
      const float* rp = roi + ((size_t)b * R_N + i) * 4;
      float x1 = rp[0], y1 = rp[1], x2 = rp[2], y2 = rp[3];
      o_roi[0] = x1; o_roi[1] = y1; o_roi[2] = x2; o_roi[3] = y2;
      int g = wgta[(size_t)b * R_N + i];
      const float* gp = gt + ((size_t)b * G_N + g) * 4;
      float gx1 = gp[0], gy1 = gp[1], gx2 = gp[2], gy2 = gp[3];
      if (scls[i]) o_lab = (float)labels[b * G_N + g];
      const float EPSF = 1.1920928955078125e-7f;  // np.finfo(f32).eps
      float w = fmaxf(x2 - x1, EPSF);
      float h = fmaxf(y2 - y1, EPSF);
      float cx = x1 + 0.5f * (x2 - x1);
      float cy = y1 + 0.5f * (y2 - y1);
      float bw = gx2 - gx1, bh = gy2 - gy1;
      float bcx = gx1 + 0.5f * bw, bcy = gy1 + 0.5f * bh;
      o_d[0] = (bcx - cx) / w;
      o_d[1] = (bcy - cy) / h;
      o_d[2] = logf(bw / w);
      o_d[3] = logf(bh / h);
    }
    float* out0 = out;                                 // [32,128,4]
    float* out1 = out + (size_t)B_IMG * NS * 4;        // [32,128]
    float* out2 = out1 + (size_t)B_IMG * NS;           // [32,128,4]
    const int base = b * NS + p;
    out0[base * 4 + 0] = o_roi[0];
    out0[base * 4 + 1] = o_roi[1];
    out0[base * 4 + 2] = o_roi[2];
    out0[base * 4 + 3] = o_roi[3];
    out1[base] = o_lab;
    out2[base * 4 + 0] = o_d[0];
    out2[base * 4 + 1] = o_d[1];
    out2[base * 4 + 2] = o_d[2];
    out2[base * 4 + 3] = o_d[3];
  }
}

extern "C" void kernel_launch(void* const* d_in, const int* in_sizes, int n_in,
                              void* d_out, int out_size, void* d_ws, size_t ws_size,
                              hipStream_t stream) {
  const float* roi    = (const float*)d_in[0];
  const float* gt     = (const float*)d_in[1];
  const int*   labels = (const int*)d_in[2];
  // d_in[3] (image) is unused by the math.

  float* wr    = (float*)d_ws;                  // [32*6000] r values
  float* wmiou = wr + (size_t)B_IMG * R_N;      // [32*6000] max IOU
  int*   wgta  = (int*)(wmiou + (size_t)B_IMG * R_N);  // [32*6000] argmax gt

  dim3 g1((R_N + 255) / 256, B_IMG);
  prep_kernel<<<g1, 256, 0, stream>>>(roi, gt, wr, wmiou, wgta);
  select_kernel<<<B_IMG, SEL_T, 0, stream>>>(roi, gt, labels, wr, wmiou, wgta,
                                             (float*)d_out);
}